// Round 12
// baseline (221.753 us; speedup 1.0000x reference)
//
#include <hip/hip_runtime.h>
#include <hip/hip_bf16.h>

// Round 16:
//   k0 cvtw, k1 qkv: FROZEN (R15/R11-verified).
//   k2 attn: 2 BLOCKS/CU. block 256 thr (4 waves), 64 q-rows/block, BN=32,
//           grid 512 = 16 b x 32 qt. LDS 64KB: 2 buffers x [K 32x256 | Vt 256x32].
//           Theory: 1-blk/CU barrier lockstep leaves LDS/MFMA pipes idle during
//           softmax/waits; a second independent block fills them. Per-(q,k)
//           LDS bytes and softmax/elem invariant. Inner math = verified R6
//           path (r<2, single ks2 P^T build). V 64B-row XOR re-derived:
//           slot = quad ^ ((d>>1)&3) -> 2-way (free). Fused-proj epilogue in
//           two 128-row Wo passes (64KB LDS). Arch VGPR ~90 < 128 cap, no spill.
// ws (ushort): Q[0], K[NE], Vt[2NE], NE=16*2048*256. Wqbf in d_out (384KB).

typedef short bf16x8 __attribute__((ext_vector_type(8)));
typedef float f32x4 __attribute__((ext_vector_type(4)));

#define MFMA16(a, b, c) __builtin_amdgcn_mfma_f32_16x16x32_bf16((a), (b), (c), 0, 0, 0)

__device__ __forceinline__ unsigned short f2bf(float f) {
  unsigned int x;
  __builtin_memcpy(&x, &f, 4);
  x = x + 0x7fffu + ((x >> 16) & 1u);
  return (unsigned short)(x >> 16);
}
__device__ __forceinline__ unsigned int pack2(float a, float b) {
  float2 t;
  t.x = a;
  t.y = b;
  __hip_bfloat162 h = __float22bfloat162_rn(t);
  unsigned int u;
  __builtin_memcpy(&u, &h, 4);
  return u;
}

// async 16B global->LDS. LDS dest is wave-uniform base + lane*16 (HW rule).
typedef __attribute__((address_space(3))) void as3_void;
typedef __attribute__((address_space(1))) const void as1_void;
__device__ __forceinline__ void gl_lds16(const void* g, void* l) {
  __builtin_amdgcn_global_load_lds((as1_void*)(unsigned long long)g,
                                   (as3_void*)(unsigned int)(unsigned long long)l,
                                   16, 0, 0);
}

// ---------------- W_qkv pre-convert (fp32 -> bf16, pre-swizzled) ----------------
__global__ __launch_bounds__(256, 4) void cvtw_kernel(
    const float* __restrict__ W, unsigned short* __restrict__ Wbf) {
  int idx = blockIdx.x * 256 + threadIdx.x;
  int row = idx >> 5, sc = idx & 31;
  int c = (sc & 24) | ((sc ^ (row & 7)) & 7);
  const float* wp = W + (size_t)row * 256 + c * 8;
  float4 a0 = *(const float4*)wp, a1 = *(const float4*)(wp + 4);
  uint4 u;
  u.x = pack2(a0.x, a0.y);
  u.y = pack2(a0.z, a0.w);
  u.z = pack2(a1.x, a1.y);
  u.w = pack2(a1.z, a1.w);
  *(uint4*)(Wbf + (size_t)idx * 8) = u;
}

// ---------------- QKV GEMM (R11-verified, frozen) ----------------
__global__ __launch_bounds__(256, 2) void qkv_kernel(
    const float* __restrict__ X, const unsigned short* __restrict__ Wqbf,
    unsigned short* __restrict__ Q, unsigned short* __restrict__ Kp,
    unsigned short* __restrict__ Vt) {
  __shared__ unsigned short Al[64 * 256];  // 32KB
  __shared__ unsigned short Bl[64 * 256];  // 32KB
  const int m0 = blockIdx.x * 64;
  const int t = threadIdx.x;
  const int w = t >> 6, lane = t & 63, lo = lane & 15, quad = lane >> 4;
  const int wr = (w >> 1) * 32, wc = (w & 1) * 32;

#pragma unroll
  for (int r = 0; r < 8; ++r) {
    int ci = r * 256 + t;
    int row = ci >> 5, c = ci & 31;
    int s = (c & 24) | ((c ^ (row & 7)) & 7);
    const float* xp = X + (size_t)(m0 + row) * 256 + c * 8;
    float4 a0 = *(const float4*)xp, a1 = *(const float4*)(xp + 4);
    uint4 ua;
    ua.x = pack2(a0.x, a0.y);
    ua.y = pack2(a0.z, a0.w);
    ua.z = pack2(a1.x, a1.y);
    ua.w = pack2(a1.z, a1.w);
    *(uint4*)(&Al[row * 256 + s * 8]) = ua;
  }
  __syncthreads();

  bf16x8 af2[2][8];
#pragma unroll
  for (int kc = 0; kc < 8; ++kc) {
    const int c = kc * 4 + quad;
    const int jj = (c & 24) | ((c ^ (lo & 7)) & 7);
#pragma unroll
    for (int mt = 0; mt < 2; ++mt)
      af2[mt][kc] = *(const bf16x8*)(&Al[(wr + mt * 16 + lo) * 256 + jj * 8]);
  }

  const int lofs = __builtin_amdgcn_readfirstlane(w * 64 * 8);
  for (int n = 0; n < 12; ++n) {
    const int n0 = n * 64;
    __syncthreads();
    {
      const unsigned short* Wb = Wqbf + (size_t)n0 * 256;
#pragma unroll
      for (int r = 0; r < 8; ++r)
        gl_lds16(Wb + (size_t)(r * 256 + t) * 8, &Bl[r * 256 * 8 + lofs]);
    }
    asm volatile("s_waitcnt vmcnt(0)" ::: "memory");
    __syncthreads();

    f32x4 zero4 = {0.f, 0.f, 0.f, 0.f};
    f32x4 acc[2][2];
#pragma unroll
    for (int i = 0; i < 2; i++)
#pragma unroll
      for (int j = 0; j < 2; j++) acc[i][j] = zero4;

    if (n0 < 512) {
#pragma unroll
      for (int kc = 0; kc < 8; ++kc) {
        const int c = kc * 4 + quad;
        const int jj = (c & 24) | ((c ^ (lo & 7)) & 7);
        bf16x8 bfr[2];
#pragma unroll
        for (int nt = 0; nt < 2; ++nt)
          bfr[nt] = *(const bf16x8*)(&Bl[(wc + nt * 16 + lo) * 256 + jj * 8]);
#pragma unroll
        for (int mt = 0; mt < 2; ++mt)
#pragma unroll
          for (int nt = 0; nt < 2; ++nt)
            acc[mt][nt] = MFMA16(bfr[nt], af2[mt][kc], acc[mt][nt]);
      }
      unsigned short* dst = (n0 < 256) ? Q : Kp;
      const int nbase = (n0 < 256) ? n0 : n0 - 256;
#pragma unroll
      for (int mt = 0; mt < 2; ++mt)
#pragma unroll
        for (int nt = 0; nt < 2; ++nt) {
          int m = m0 + wr + mt * 16 + lo;
          int nn = nbase + wc + nt * 16 + quad * 4;
          uint2 v;
          v.x = pack2(acc[mt][nt][0], acc[mt][nt][1]);
          v.y = pack2(acc[mt][nt][2], acc[mt][nt][3]);
          *(uint2*)(dst + (size_t)m * 256 + nn) = v;
        }
    } else {
#pragma unroll
      for (int kc = 0; kc < 8; ++kc) {
        const int c = kc * 4 + quad;
        const int jj = (c & 24) | ((c ^ (lo & 7)) & 7);
        bf16x8 bfr[2];
#pragma unroll
        for (int nt = 0; nt < 2; ++nt)
          bfr[nt] = *(const bf16x8*)(&Bl[(wc + nt * 16 + lo) * 256 + jj * 8]);
#pragma unroll
        for (int mt = 0; mt < 2; ++mt)
#pragma unroll
          for (int nt = 0; nt < 2; ++nt)
            acc[mt][nt] = MFMA16(af2[mt][kc], bfr[nt], acc[mt][nt]);
      }
#pragma unroll
      for (int mt = 0; mt < 2; ++mt)
#pragma unroll
        for (int nt = 0; nt < 2; ++nt) {
          int m = m0 + wr + mt * 16 + quad * 4;
          int d = n0 + wc + nt * 16 + lo - 512;
          int b = m >> 11, s = m & 2047;
          uint2 v;
          v.x = pack2(acc[mt][nt][0], acc[mt][nt][1]);
          v.y = pack2(acc[mt][nt][2], acc[mt][nt][3]);
          *(uint2*)(Vt + ((size_t)(b * 256 + d)) * 2048 + s) = v;
        }
    }
  }
}

// ---------------- Flash attention + fused proj, 2 blocks/CU ----------------
// grid(512) = 16 b x 32 qt. block 256 = 4 waves, wave owns 16 q-rows.
// BN=32, 64 iters. LDS buf p in {0,1} (16384 ushorts): [K 32x256 | V^T 256x32].
//   K chunk (row,j) holds global col-chunk (j&16)|((j^(row&15))&15).
//   V chunk (d,vs) holds global s-chunk vs^((d>>1)&3)  (64B rows, 2-way free).
__global__ __launch_bounds__(256, 2) void attn_kernel(
    const unsigned short* __restrict__ Q, const unsigned short* __restrict__ K,
    const unsigned short* __restrict__ Vt, const float* __restrict__ Wo,
    const float* __restrict__ bias, float* __restrict__ out) {
  __shared__ __attribute__((aligned(16))) unsigned short smem[32768];  // 65536 B
  const int id = blockIdx.x;
  const int b = id & 15;
  const int qt = id >> 4;  // 0..31
  const int t = threadIdx.x;
  const int w = t >> 6, lane = t & 63, lo = lane & 15, quad = lane >> 4;
  constexpr float SCALE_LOG2E = 0.0625f * 1.4426950408889634f;

  const unsigned short* Kb = K + (size_t)b * 2048 * 256;
  const unsigned short* Vb = Vt + (size_t)b * 256 * 2048;

  // staging: 4 K chunks + 4 V chunks per thread
  unsigned int gkoff[4], gvoff[4];
  int loK[4], loV[4];
#pragma unroll
  for (int r = 0; r < 4; ++r) {
    int ck = r * 256 + t;  // K: 1024 chunks, row=ck>>5 (0..31), j=ck&31
    int krow = ck >> 5, j = ck & 31;
    int srcj = (j & 16) | ((j ^ (krow & 15)) & 15);
    gkoff[r] = (unsigned int)((krow * 256 + srcj * 8) * 2);
    loK[r] = __builtin_amdgcn_readfirstlane((r * 256 + w * 64) * 8);

    int cv = r * 256 + t;  // V: 1024 chunks, d=cv>>2 (0..255), vs=cv&3
    int vd = cv >> 2, vs = cv & 3;
    int vsrc = vs ^ ((vd >> 1) & 3);
    gvoff[r] = (unsigned int)((vd * 2048 + vsrc * 8) * 2);
    loV[r] = __builtin_amdgcn_readfirstlane(8192 + (r * 256 + w * 64) * 8);
  }

  const int qrow = b * 2048 + qt * 64 + w * 16 + lo;
  const unsigned short* qp = Q + (size_t)qrow * 256;
  bf16x8 qf[8];
#pragma unroll
  for (int ks = 0; ks < 8; ++ks)
    qf[ks] = *(const bf16x8*)(qp + ks * 32 + quad * 8);

  f32x4 zero4 = {0.f, 0.f, 0.f, 0.f};
  f32x4 oacc[16];
#pragma unroll
  for (int i = 0; i < 16; i++) oacc[i] = zero4;
  float m_run = -1e30f, l_run = 0.f;

  // prologue: prefetch iter 0 into buffer 0
#pragma unroll
  for (int r = 0; r < 4; ++r) {
    gl_lds16((const char*)Kb + gkoff[r], &smem[loK[r]]);
    gkoff[r] += 32 * 256 * 2;
  }
#pragma unroll
  for (int r = 0; r < 4; ++r) {
    gl_lds16((const char*)Vb + gvoff[r], &smem[loV[r]]);
    gvoff[r] += 32 * 2;
  }

  const int vslot = quad ^ ((lo >> 1) & 3);  // lane-constant V read slot
  for (int it = 0; it < 64; ++it) {
    asm volatile("s_waitcnt vmcnt(0)" ::: "memory");
    __syncthreads();
    if (it < 63) {
      const int pn = ((it + 1) & 1) * 16384;
#pragma unroll
      for (int r = 0; r < 4; ++r) {
        gl_lds16((const char*)Kb + gkoff[r], &smem[pn + loK[r]]);
        gkoff[r] += 32 * 256 * 2;
      }
#pragma unroll
      for (int r = 0; r < 4; ++r) {
        gl_lds16((const char*)Vb + gvoff[r], &smem[pn + loV[r]]);
        gvoff[r] += 32 * 2;
      }
    }
    const unsigned short* Kl = smem + (it & 1) * 16384;
    const unsigned short* Vl = Kl + 8192;

    // S^T[32 k][16 q]: A = K rows (2 row-tiles), B = Q frags
    f32x4 sacc[2];
    sacc[0] = zero4;
    sacc[1] = zero4;
    __builtin_amdgcn_s_setprio(1);
#pragma unroll
    for (int ks = 0; ks < 8; ++ks) {
      const int c = ks * 4 + quad;
      const int jj = (c & 16) | ((c ^ lo) & 15);
#pragma unroll
      for (int r = 0; r < 2; ++r) {
        bf16x8 kf = *(const bf16x8*)(&Kl[(r * 16 + lo) * 256 + jj * 8]);
        sacc[r] = MFMA16(kf, qf[ks], sacc[r]);
      }
    }
    __builtin_amdgcn_s_setprio(0);

    // online softmax: lane owns q=lo; 8 k-vals; reduce across quads
    float p[2][4];
    float cmax = -1e30f;
#pragma unroll
    for (int r = 0; r < 2; r++)
#pragma unroll
      for (int i = 0; i < 4; i++) {
        p[r][i] = sacc[r][i] * SCALE_LOG2E;
        cmax = fmaxf(cmax, p[r][i]);
      }
    cmax = fmaxf(cmax, __shfl_xor(cmax, 16));
    cmax = fmaxf(cmax, __shfl_xor(cmax, 32));
    if (!__all(cmax <= m_run + 8.f)) {  // T13 defer-rescale
      float mnew = fmaxf(m_run, cmax);
      float alpha = exp2f(m_run - mnew);
      l_run *= alpha;
#pragma unroll
      for (int i = 0; i < 16; i++) oacc[i] *= alpha;
      m_run = mnew;
    }
    float rsum = 0.f;
#pragma unroll
    for (int r = 0; r < 2; r++)
#pragma unroll
      for (int i = 0; i < 4; i++) {
        p[r][i] = exp2f(p[r][i] - m_run);
        rsum += p[r][i];
      }
    rsum += __shfl_xor(rsum, 16);
    rsum += __shfl_xor(rsum, 32);
    l_run += rsum;

    unsigned int pk[2][2];
#pragma unroll
    for (int r = 0; r < 2; r++) {
      pk[r][0] = pack2(p[r][0], p[r][1]);
      pk[r][1] = pack2(p[r][2], p[r][3]);
    }

    // P^T B-frag (verified single ks2-block build) + PV
    union {
      unsigned int u[4];
      bf16x8 v;
    } cvt;
#pragma unroll
    for (int dd = 0; dd < 4; ++dd) {
      int src = lo + 16 * ((2 * quad + (dd >> 1)) & 3);
      unsigned int v0 = (unsigned int)__shfl((int)pk[0][dd & 1], src);
      unsigned int v1 = (unsigned int)__shfl((int)pk[1][dd & 1], src);
      cvt.u[dd] = (quad >> 1) ? v1 : v0;
    }
    bf16x8 pf = cvt.v;
    __builtin_amdgcn_s_setprio(1);
#pragma unroll
    for (int dt = 0; dt < 16; ++dt) {
      bf16x8 vf = *(const bf16x8*)(&Vl[(dt * 16 + lo) * 32 + vslot * 8]);
      oacc[dt] = MFMA16(vf, pf, oacc[dt]);
    }
    __builtin_amdgcn_s_setprio(0);
  }

  // ================= fused output projection (two 128-row Wo passes) =======
  float inv = 1.0f / l_run;
  uint2 c2[16];
#pragma unroll
  for (int dt = 0; dt < 16; ++dt) {
    c2[dt].x = pack2(oacc[dt][0] * inv, oacc[dt][1] * inv);
    c2[dt].y = pack2(oacc[dt][2] * inv, oacc[dt][3] * inv);
  }

  for (int h = 0; h < 2; ++h) {
    __syncthreads();  // prev users of smem done
    // stage Wo rows [h*128, h*128+128) fp32->bf16, chunk-XOR swizzled
#pragma unroll
    for (int r = 0; r < 16; ++r) {
      int ci = r * 256 + t;
      int row = ci >> 5, c = ci & 31;
      int s = (c & 24) | ((c ^ (row & 7)) & 7);
      const float* wp = Wo + (size_t)(h * 128 + row) * 256 + c * 8;
      float4 a0 = *(const float4*)wp, a1 = *(const float4*)(wp + 4);
      uint4 ua;
      ua.x = pack2(a0.x, a0.y);
      ua.y = pack2(a0.z, a0.w);
      ua.z = pack2(a1.x, a1.y);
      ua.w = pack2(a1.z, a1.w);
      *(uint4*)(&smem[row * 256 + s * 8]) = ua;
    }
    __syncthreads();

    f32x4 outacc[8];
#pragma unroll
    for (int i = 0; i < 8; i++) outacc[i] = zero4;

#pragma unroll
    for (int ks = 0; ks < 8; ++ks) {
      int sa = lo + 16 * ((quad & 1) * 2);
      unsigned int xA = (unsigned int)__shfl((int)c2[2 * ks].x, sa);
      unsigned int yA = (unsigned int)__shfl((int)c2[2 * ks].y, sa);
      unsigned int xB = (unsigned int)__shfl((int)c2[2 * ks].x, sa + 16);
      unsigned int yB = (unsigned int)__shfl((int)c2[2 * ks].y, sa + 16);
      unsigned int xA1 = (unsigned int)__shfl((int)c2[2 * ks + 1].x, sa);
      unsigned int yA1 = (unsigned int)__shfl((int)c2[2 * ks + 1].y, sa);
      unsigned int xB1 = (unsigned int)__shfl((int)c2[2 * ks + 1].x, sa + 16);
      unsigned int yB1 = (unsigned int)__shfl((int)c2[2 * ks + 1].y, sa + 16);
      union {
        unsigned int u[4];
        bf16x8 v;
      } cv2;
      bool hiq = (quad >> 1) != 0;
      cv2.u[0] = hiq ? xA1 : xA;
      cv2.u[1] = hiq ? yA1 : yA;
      cv2.u[2] = hiq ? xB1 : xB;
      cv2.u[3] = hiq ? yB1 : yB;
      bf16x8 pf = cv2.v;

      const int c = ks * 4 + quad;
      const int jj = (c & 24) | ((c ^ (lo & 7)) & 7);
      __builtin_amdgcn_s_setprio(1);
#pragma unroll
      for (int et = 0; et < 8; ++et) {
        bf16x8 af = *(const bf16x8*)(&smem[(et * 16 + lo) * 256 + jj * 8]);
        outacc[et] = MFMA16(af, pf, outacc[et]);
      }
      __builtin_amdgcn_s_setprio(0);
    }

    float* op = out + (size_t)qrow * 256 + h * 128;
#pragma unroll
    for (int et = 0; et < 8; ++et) {
      const float4 b4 = *(const float4*)(bias + h * 128 + et * 16 + quad * 4);
      float4 v;
      v.x = outacc[et][0] + b4.x;
      v.y = outacc[et][1] + b4.y;
      v.z = outacc[et][2] + b4.z;
      v.w = outacc[et][3] + b4.w;
      *(float4*)(op + et * 16 + quad * 4) = v;
    }
  }
}

extern "C" void kernel_launch(void* const* d_in, const int* in_sizes, int n_in,
                              void* d_out, int out_size, void* d_ws, size_t ws_size,
                              hipStream_t stream) {
  const float* X = (const float*)d_in[0];
  const float* Wq = (const float*)d_in[1];
  const float* Wo = (const float*)d_in[2];
  const float* Bo = (const float*)d_in[3];
  float* out = (float*)d_out;
  unsigned short* ws = (unsigned short*)d_ws;

  const size_t NE = (size_t)16 * 2048 * 256;
  unsigned short* Qb = ws;
  unsigned short* Kb = ws + NE;
  unsigned short* Vt = ws + 2 * NE;
  unsigned short* Wqbf = (unsigned short*)d_out;  // dead until attn writes out

  cvtw_kernel<<<dim3(96), 256, 0, stream>>>(Wq, Wqbf);
  qkv_kernel<<<dim3(512), 256, 0, stream>>>(X, Wqbf, Qb, Kb, Vt);
  attn_kernel<<<dim3(512), 256, 0, stream>>>(Qb, Kb, Vt, Wo, Bo, out);
}